// Round 11
// baseline (9230.859 us; speedup 1.0000x reference)
//
#include <hip/hip_runtime.h>
#include <hip/hip_fp16.h>
#include <stdint.h>

// DagCellTorch R11: MFMA recurrence, software-pipelined weight stream.
// 32 blocks x 1024 threads (16 waves), __launch_bounds__(1024,4) -> 128 VGPR.
// Step = 9 uniform units (X, H, E0..E6), each: 16 MFMA (2 matrices) + prefetch
// of the NEXT unit's 16 weight uint4s into registers (weights are h-independent,
// so the prefetch crosses the barrier logically ahead of need by ~1 unit).
// Math/layout identical to R10 (passed, absmax 1.95e-3). NT hints on x/out to
// keep the 2.25 MB weight set L2-resident (R10: 4.28 GB HBM refetch).

#define T_STEPS 128
#define B_ROWS  512
#define NH      256
#define BM      16
#define NBLK    (B_ROWS/BM)   // 32
#define NTHR    1024
#define KSTEPS  8             // K=256 / 32

typedef _Float16 half8_t __attribute__((ext_vector_type(8)));
typedef float    f32x4_t __attribute__((ext_vector_type(4)));
typedef float    fvec4   __attribute__((ext_vector_type(4)));
union U4H8 { uint4 u; half8_t h; };

__device__ __forceinline__ float sigmoidf_(float x){
  float e = __expf(-fabsf(x));
  float s = 1.f/(1.f+e);
  return x>=0.f ? s : 1.f-s;
}
__device__ __forceinline__ float tanhf_(float x){
  float e = __expf(-2.f*fabsf(x));
  float r = (1.f-e)/(1.f+e);
  return x>=0.f ? r : -r;
}
__device__ __forceinline__ unsigned short f2h(float f){
  return __half_as_ushort(__float2half(f));   // RNE
}
__device__ __forceinline__ uint32_t packh(float a, float b){
  return (uint32_t)f2h(a) | ((uint32_t)f2h(b) << 16);
}

template<int ACT>  // 0 relu, 1 tanh, 2 sigmoid, 3 identity
__device__ __forceinline__ float actf(float v){
  if constexpr (ACT==0)      return fmaxf(v, 0.f);
  else if constexpr (ACT==1) return tanhf_(v);
  else if constexpr (ACT==2) return sigmoidf_(v);
  else                       return v;
}

// B-fragment weight pack (verified in R10). dword idx =
// ((((p*2+mat)*16+ct)*8+ks)*64+lane)*4+dw ; col = ct*16+(lane&15),
// k = ks*32+(lane>>4)*8+dw*2 -> packh(W[col][k], W[col][k+1])
__global__ void prep_weights(const float* __restrict__ wxc, const float* __restrict__ wxh,
                             const float* __restrict__ whc, const float* __restrict__ whh,
                             const float* __restrict__ Wc,  const float* __restrict__ Wh,
                             uint32_t* __restrict__ WM){
  int idx = blockIdx.x*256 + threadIdx.x;
  if (idx >= 9*2*16*8*64*4) return;
  int dw   = idx & 3;
  int lane = (idx >> 2) & 63;
  int ks   = (idx >> 8) & 7;
  int ct   = (idx >> 11) & 15;
  int mat  = (idx >> 15) & 1;
  int p    = idx >> 16;
  int col  = ct*16 + (lane & 15);
  int k    = ks*32 + (lane >> 4)*8 + dw*2;
  const float* M;
  if (p == 0)      M = mat ? wxh : wxc;
  else if (p == 1) M = mat ? whh : whc;
  else             M = (mat ? Wh : Wc) + (size_t)(p-2)*NH*NH;
  WM[idx] = packh(M[(size_t)col*NH + k], M[(size_t)col*NH + k + 1]);
}

// C/D frag (row=4g+r, col=ct*16+n) -> A-frag LDS layout (verified in R10).
__device__ __forceinline__ void write_hA(uint4 (* __restrict__ dst)[4][16],
                                         int ct, int lane, const float* hn)
{
  const int n = lane & 15, g = lane >> 4;
  float q0 = __shfl_xor(hn[0], 1);
  float q1 = __shfl_xor(hn[1], 1);
  float q2 = __shfl_xor(hn[2], 1);
  float q3 = __shfl_xor(hn[3], 1);
  if (!(lane & 1)){
    int ks  = ct >> 1;
    int g2  = ((ct & 1) << 1) | (n >> 3);
    int dwi = (n & 7) >> 1;
    ((uint32_t*)&dst[ks][g2][4*g + 0])[dwi] = packh(hn[0], q0);
    ((uint32_t*)&dst[ks][g2][4*g + 1])[dwi] = packh(hn[1], q1);
    ((uint32_t*)&dst[ks][g2][4*g + 2])[dwi] = packh(hn[2], q2);
    ((uint32_t*)&dst[ks][g2][4*g + 3])[dwi] = packh(hn[3], q3);
  }
}

// ---- unit building blocks (textual macros; names resolve inside the kernel) ----
// weight uint4 address: wbase + im*8192 + ks*64   (wbase = WM4 + ct*512 + lane)
#define PREF_A(IM) _Pragma("unroll") \
  for (int ks_=0; ks_<KSTEPS; ++ks_) nwA[ks_] = wbase[(IM)*8192 + ks_*64];
#define PREF_B(IM) _Pragma("unroll") \
  for (int ks_=0; ks_<KSTEPS; ++ks_) nwB[ks_] = wbase[(IM)*8192 + ks_*64];
#define PASS_A(SRC) _Pragma("unroll") \
  for (int ks_=0; ks_<KSTEPS; ++ks_){ U4H8 a_, b_; \
    a_.u = (SRC)[ks_][g][n]; b_.u = cwA[ks_]; \
    accA = __builtin_amdgcn_mfma_f32_16x16x32_f16(a_.h, b_.h, accA, 0,0,0); }
#define PASS_B(SRC) _Pragma("unroll") \
  for (int ks_=0; ks_<KSTEPS; ++ks_){ U4H8 a_, b_; \
    a_.u = (SRC)[ks_][g][n]; b_.u = cwB[ks_]; \
    accB = __builtin_amdgcn_mfma_f32_16x16x32_f16(a_.h, b_.h, accB, 0,0,0); }
#define ROT _Pragma("unroll") \
  for (int ks_=0; ks_<KSTEPS; ++ks_){ cwA[ks_] = nwA[ks_]; cwB[ks_] = nwB[ks_]; }

#define EDGE_UNIT(IMNA, IMNB, ACT_) { \
  PREF_A(IMNA) \
  PASS_A(hA[buf]) \
  PREF_B(IMNB) \
  PASS_B(hA[buf]) \
  float hn[4]; \
  _Pragma("unroll") for (int r=0;r<4;++r){ \
    float c = sigmoidf_(accA[r]); \
    float f = actf<ACT_>(accB[r]); \
    hn[r] = c*f + (1.f-c)*hold[r]; hold[r] = hn[r]; } \
  write_hA(hA[buf^1], ct, lane, hn); \
  __syncthreads(); buf ^= 1; ROT \
  accA = (f32x4_t){0.f,0.f,0.f,0.f}; accB = (f32x4_t){0.f,0.f,0.f,0.f}; }

__global__ __launch_bounds__(NTHR, 4) void dag_mfma(
    const float* __restrict__ x,    // (T,B,NH) f32
    const float* __restrict__ h0,   // (B,NH) f32
    const float* __restrict__ bxc,  // (NH)
    const float* __restrict__ bxh,  // (NH)
    const uint32_t* __restrict__ WM,
    float* __restrict__ out)        // T*B*NH outputs then B*NH final hidden
{
  __shared__ uint4 hA[2][KSTEPS][4][16];   // 16 KB fp16 h, A-frag layout, dbuf
  __shared__ uint4 xA[KSTEPS][4][16];      // 8 KB fp16 x_t, A-frag layout
  __shared__ float redL[16][16];
  __shared__ float scaleL[16];

  const int tid  = threadIdx.x;
  const int lane = tid & 63;
  const int ct   = tid >> 6;       // wave id = col-tile
  const int n    = lane & 15;
  const int g    = lane >> 4;
  const int col  = ct*16 + n;
  const int r0   = blockIdx.x * BM;
  const uint4* wbase = (const uint4*)WM + (size_t)ct*512 + lane;

  const float bcv = bxc[col];
  const float bhv = bxh[col];

  float hold[4];
  #pragma unroll
  for (int r = 0; r < 4; ++r)
    hold[r] = h0[(size_t)(r0 + 4*g + r)*NH + col];
  write_hA(hA[0], ct, lane, hold);

  {  // xA for t=0
    fvec4 xv = __builtin_nontemporal_load(
        (const fvec4*)x + ((size_t)0*B_ROWS + r0 + (tid >> 6))*64 + (tid & 63));
    int m2 = tid >> 6, k0 = (tid & 63)*4;
    int ks2 = k0 >> 5, g3 = (k0 >> 3) & 3, ih = (k0 & 7) >> 2;
    uint2 pk = make_uint2(packh(xv.x, xv.y), packh(xv.z, xv.w));
    ((uint2*)&xA[ks2][g3][m2])[ih] = pk;
  }

  // preload unit-X weights (im 0,1)
  uint4 cwA[KSTEPS], cwB[KSTEPS], nwA[KSTEPS], nwB[KSTEPS];
  #pragma unroll
  for (int ks_ = 0; ks_ < KSTEPS; ++ks_){
    cwA[ks_] = wbase[0*8192 + ks_*64];
    cwB[ks_] = wbase[1*8192 + ks_*64];
  }
  __syncthreads();

  int buf = 0;
  for (int t = 0; t < T_STEPS; ++t){
    f32x4_t accA = {bcv, bcv, bcv, bcv};
    f32x4_t accB = {bhv, bhv, bhv, bhv};

    // ===== unit X: A = xA, weights im 0,1; prefetch H (im 2,3); no barrier
    PREF_A(2)
    PASS_A(xA)
    PREF_B(3)
    PASS_B(xA)
    ROT

    // ===== unit H: A = hA[buf], weights im 2,3; prefetch E0 (im 4,5); node-0 gate
    {
      PREF_A(4)
      PASS_A(hA[buf])
      PREF_B(5)
      PASS_B(hA[buf])
      float hn[4];
      #pragma unroll
      for (int r = 0; r < 4; ++r){
        float c = sigmoidf_(accA[r]);
        float f = tanhf_(accB[r]);
        hn[r] = c*f + (1.f-c)*hold[r]; hold[r] = hn[r];
      }
      write_hA(hA[buf^1], ct, lane, hn);
      __syncthreads(); buf ^= 1; ROT
      accA = (f32x4_t){0.f,0.f,0.f,0.f}; accB = (f32x4_t){0.f,0.f,0.f,0.f};
    }

    // ===== unit E0 (relu) + x(t+1) NT load; prefetch E1 (im 6,7)
    {
      const bool doX = (t + 1 < T_STEPS);
      fvec4 xv;
      if (doX) xv = __builtin_nontemporal_load(
          (const fvec4*)x + ((size_t)(t+1)*B_ROWS + r0 + (tid >> 6))*64 + (tid & 63));
      PREF_A(6)
      PASS_A(hA[buf])
      PREF_B(7)
      PASS_B(hA[buf])
      float hn[4];
      #pragma unroll
      for (int r = 0; r < 4; ++r){
        float c = sigmoidf_(accA[r]);
        float f = fmaxf(accB[r], 0.f);
        hn[r] = c*f + (1.f-c)*hold[r]; hold[r] = hn[r];
      }
      write_hA(hA[buf^1], ct, lane, hn);
      if (doX){
        int m2 = tid >> 6, k0 = (tid & 63)*4;
        int ks2 = k0 >> 5, g3 = (k0 >> 3) & 3, ih = (k0 & 7) >> 2;
        uint2 pk = make_uint2(packh(xv.x, xv.y), packh(xv.z, xv.w));
        ((uint2*)&xA[ks2][g3][m2])[ih] = pk;
      }
      __syncthreads(); buf ^= 1; ROT
      accA = (f32x4_t){0.f,0.f,0.f,0.f}; accB = (f32x4_t){0.f,0.f,0.f,0.f};
    }

    // ===== units E1..E5 (tanh, sigmoid, identity, relu, tanh)
    EDGE_UNIT(8,  9,  1)
    EDGE_UNIT(10, 11, 2)
    EDGE_UNIT(12, 13, 3)
    EDGE_UNIT(14, 15, 0)
    EDGE_UNIT(16, 17, 1)

    // ===== unit E6 (identity) + norm clip + output; prefetch next-step X (im 0,1)
    {
      PREF_A(0)
      PASS_A(hA[buf])
      PREF_B(1)
      PASS_B(hA[buf])
      float hn[4];
      #pragma unroll
      for (int r = 0; r < 4; ++r){
        float c = sigmoidf_(accA[r]);
        hn[r] = c*accB[r] + (1.f-c)*hold[r];
      }
      #pragma unroll
      for (int r = 0; r < 4; ++r){
        float v = hn[r]*hn[r];
        v += __shfl_xor(v, 1); v += __shfl_xor(v, 2);
        v += __shfl_xor(v, 4); v += __shfl_xor(v, 8);
        if (n == 0) redL[ct][4*g + r] = v;
      }
      __syncthreads();
      if (ct == 0){
        float tot = 0.f;
        #pragma unroll
        for (int c2 = 0; c2 < 16; ++c2) tot += redL[c2][n];
        float nrm = sqrtf(tot);
        scaleL[n] = (nrm > 25.f) ? 25.f/nrm : 1.f;
      }
      __syncthreads();
      #pragma unroll
      for (int r = 0; r < 4; ++r){
        float sc = scaleL[4*g + r];
        hn[r] *= sc;
        hold[r] = hn[r];
        __builtin_nontemporal_store(hn[r],
            &out[(size_t)t*(B_ROWS*NH) + (size_t)(r0 + 4*g + r)*NH + col]);
      }
      write_hA(hA[buf^1], ct, lane, hn);
      __syncthreads(); buf ^= 1; ROT
    }
  }

  #pragma unroll
  for (int r = 0; r < 4; ++r)
    out[(size_t)T_STEPS*(B_ROWS*NH) + (size_t)(r0 + 4*g + r)*NH + col] = hold[r];
}

extern "C" void kernel_launch(void* const* d_in, const int* in_sizes, int n_in,
                              void* d_out, int out_size, void* d_ws, size_t ws_size,
                              hipStream_t stream) {
  const float* x   = (const float*)d_in[0];
  const float* h0  = (const float*)d_in[1];
  const float* wxc = (const float*)d_in[2];
  const float* bxc = (const float*)d_in[3];
  const float* wxh = (const float*)d_in[4];
  const float* bxh = (const float*)d_in[5];
  const float* whc = (const float*)d_in[6];
  const float* whh = (const float*)d_in[7];
  const float* Wc  = (const float*)d_in[8];
  const float* Wh  = (const float*)d_in[9];
  uint32_t* WM = (uint32_t*)d_ws;   // 589824 dwords = 2.36 MB

  const int total = 9*2*16*8*64*4;
  prep_weights<<<(total + 255)/256, 256, 0, stream>>>(wxc, wxh, whc, whh, Wc, Wh, WM);
  dag_mfma<<<NBLK, NTHR, 0, stream>>>(x, h0, bxc, bxh, WM, (float*)d_out);
}